// Round 2
// baseline (706.135 us; speedup 1.0000x reference)
//
#include <hip/hip_runtime.h>
#include <hip/hip_bf16.h>

// Problem constants (RelateModel_652835029255)
#define NN 100000
#define EE 600000
#define DD 128
#define GG 256
#define CCL 16

typedef __attribute__((ext_vector_type(8))) short short8;
typedef __attribute__((ext_vector_type(4))) float f32x4;

// float32 vs bfloat16 input detection: read 1024 elements of x as bf16 and
// count plausible magnitudes. bf16 data -> ~all plausible; f32 data read as
// bf16 -> only the high halves (~50%+10% lucky mantissas) are plausible.
__global__ __launch_bounds__(256) void sniff_kernel(const void* __restrict__ xraw, int* __restrict__ flag) {
    int t = threadIdx.x;
    const unsigned short* u = (const unsigned short*)xraw;
    int good = 0;
    #pragma unroll
    for (int i = 0; i < 4; i++) {
        unsigned short b = u[t * 4 + i];
        int e = (b >> 7) & 0xFF;
        if (e >= 107 && e <= 130) good++;   // |v| in (1e-6, 32)
    }
    __shared__ int sg[256];
    sg[t] = good;
    __syncthreads();
    for (int s = 128; s > 0; s >>= 1) { if (t < s) sg[t] += sg[t + s]; __syncthreads(); }
    if (t == 0) flag[0] = (sg[0] >= 900) ? 1 : 0;   // 1 = data is bf16
}

__device__ __forceinline__ float loadf(const void* p, size_t i, int isbf) {
    if (isbf) {
        unsigned short b = ((const unsigned short*)p)[i];
        return __uint_as_float(((unsigned)b) << 16);
    }
    return ((const float*)p)[i];
}

// canonicalize x -> bf16 xc  (N*128 = 12.8M elems, 8 per thread)
__global__ __launch_bounds__(256) void convx_kernel(const void* __restrict__ xraw, const int* __restrict__ flag,
                                                    __hip_bfloat16* __restrict__ xc) {
    int isbf = flag[0];
    size_t i0 = ((size_t)blockIdx.x * 256 + threadIdx.x) * 8;
    if (i0 >= (size_t)NN * DD) return;
    if (isbf) {
        *(uint4*)(xc + i0) = *(const uint4*)((const __hip_bfloat16*)xraw + i0);
    } else {
        const float* xf = (const float*)xraw;
        #pragma unroll
        for (int j = 0; j < 8; j++) xc[i0 + j] = __float2bfloat16(xf[i0 + j]);
    }
}

// weights -> wt[mat][n][k] (transposed, bf16), mat = layer*5 + g (g0=root, g1..4=rel)
__global__ __launch_bounds__(256) void convw_kernel(const void* __restrict__ rel_raw, const void* __restrict__ root_raw,
                                                    const int* __restrict__ flag, __hip_bfloat16* __restrict__ wt) {
    int isbf = flag[0];
    int mat = blockIdx.x;                 // 0..14
    int layer = mat / 5, g = mat % 5;
    size_t srcoff = (g == 0) ? (size_t)layer * 16384 : (size_t)(layer * 4 + (g - 1)) * 16384;
    const void* sraw = (g == 0) ? root_raw : rel_raw;
    __hip_bfloat16* dstp = wt + (size_t)mat * 16384;
    for (int idx = threadIdx.x; idx < 16384; idx += 256) {
        int k = idx >> 7, n = idx & 127;
        float v = loadf(sraw, srcoff + (size_t)k * 128 + n, isbf);
        dstp[n * 128 + k] = __float2bfloat16(v);
    }
}

// small params -> one f32 block:
// [0]bias(384) [384]bng(256) [640]bnb(256) [896]bnm(256) [1152]bnv(256)
// [1408]w1(8192) [9600]b1(64) [9664]w2(1024) [10688]b2(16)   total 10704
__global__ __launch_bounds__(256) void convp_kernel(const void* bias, const void* bng, const void* bnb,
                                                    const void* bnm, const void* bnv, const void* w1,
                                                    const void* b1, const void* w2, const void* b2,
                                                    const int* __restrict__ flag, float* __restrict__ pf) {
    int isbf = flag[0];
    const void* srcs[9] = {bias, bng, bnb, bnm, bnv, w1, b1, w2, b2};
    const int cnts[9] = {384, 256, 256, 256, 256, 8192, 64, 1024, 16};
    const int offs[9] = {0, 384, 640, 896, 1152, 1408, 9600, 9664, 10688};
    int b = blockIdx.x;
    const void* s = srcs[b];
    int c = cnts[b], o = offs[b];
    for (int i = threadIdx.x; i < c; i += 256) pf[o + i] = loadf(s, i, isbf);
}

// ---------------- CSR build ----------------
__global__ __launch_bounds__(256) void count_kernel(const int* __restrict__ dst, int* __restrict__ cnt) {
    int e = blockIdx.x * 256 + threadIdx.x;
    if (e < EE) atomicAdd(&cnt[dst[e]], 1);
}

__global__ __launch_bounds__(256) void alloc_kernel(const int* __restrict__ cnt, int* __restrict__ counter,
                                                    int* __restrict__ startp, int* __restrict__ wptr) {
    int n = blockIdx.x * 256 + threadIdx.x;
    int lane = threadIdx.x & 63;
    int c = (n < NN) ? cnt[n] : 0;
    int v = c;
    #pragma unroll
    for (int d = 1; d < 64; d <<= 1) {
        int o = __shfl_up(v, d);
        if (lane >= d) v += o;
    }
    int base = 0;
    if (lane == 63) base = atomicAdd(counter, v);   // v at lane63 = wave total (inclusive)
    base = __shfl(base, 63);
    if (n < NN) {
        int s = base + v - c;   // exclusive within wave
        startp[n] = s;
        wptr[n]  = s;
    }
}

__global__ __launch_bounds__(256) void fill_kernel(const int* __restrict__ src, const int* __restrict__ dst,
                                                   const int* __restrict__ et, int* __restrict__ wptr,
                                                   int* __restrict__ elist) {
    int e = blockIdx.x * 256 + threadIdx.x;
    if (e < EE) {
        int d = dst[e];
        int pos = atomicAdd(&wptr[d], 1);
        elist[pos] = src[e] | (et[e] << 17);   // src < 2^17, type in 2 bits
    }
}

// ---------------- per-node mean aggregation: xagg[n][r*128+d] (bf16, already /cnt) ----------------
__global__ __launch_bounds__(256) void agg_kernel(const __hip_bfloat16* __restrict__ h,
                                                  const int* __restrict__ elist,
                                                  const int* __restrict__ startp,
                                                  const int* __restrict__ cnt,
                                                  __hip_bfloat16* __restrict__ xagg) {
    int wid = (blockIdx.x * 256 + threadIdx.x) >> 6;   // one wave per node
    int lane = threadIdx.x & 63;
    if (wid >= NN) return;
    int s = startp[wid], c = cnt[wid];
    float a0x=0,a0y=0,a1x=0,a1y=0,a2x=0,a2y=0,a3x=0,a3y=0;
    int c0=0,c1=0,c2=0,c3=0;
    int my = (lane < c) ? elist[s + lane] : 0;
    for (int e = 0; e < c; e++) {
        int packed = (e < 64) ? __shfl(my, e) : elist[s + e];
        int srcn = packed & 0x1FFFF;
        int r = (packed >> 17) & 3;
        __hip_bfloat162 v = ((const __hip_bfloat162*)(h + (size_t)srcn * DD))[lane];
        float vx = __bfloat162float(v.x), vy = __bfloat162float(v.y);
        if (r == 0)      { a0x += vx; a0y += vy; c0++; }
        else if (r == 1) { a1x += vx; a1y += vy; c1++; }
        else if (r == 2) { a2x += vx; a2y += vy; c2++; }
        else             { a3x += vx; a3y += vy; c3++; }
    }
    __hip_bfloat162* out = (__hip_bfloat162*)(xagg + (size_t)wid * 512);
    float i0 = 1.0f / (float)(c0 ? c0 : 1), i1 = 1.0f / (float)(c1 ? c1 : 1);
    float i2 = 1.0f / (float)(c2 ? c2 : 1), i3 = 1.0f / (float)(c3 ? c3 : 1);
    __hip_bfloat162 o;
    o.x = __float2bfloat16(a0x * i0); o.y = __float2bfloat16(a0y * i0); out[lane]       = o;
    o.x = __float2bfloat16(a1x * i1); o.y = __float2bfloat16(a1y * i1); out[64 + lane]  = o;
    o.x = __float2bfloat16(a2x * i2); o.y = __float2bfloat16(a2y * i2); out[128 + lane] = o;
    o.x = __float2bfloat16(a3x * i3); o.y = __float2bfloat16(a3y * i3); out[192 + lane] = o;
}

// ---------------- fused GEMM: out[n][:] = [h | agg] @ [Wroot; W0..W3] + bias (+res, +BN, +ELU) ----
__global__ __launch_bounds__(256) void gemm_kernel(const __hip_bfloat16* __restrict__ h_in,
                                                   const __hip_bfloat16* __restrict__ xagg,
                                                   const __hip_bfloat16* __restrict__ wt,   // [5][128][128] n-major
                                                   const float* __restrict__ bias,
                                                   const float* __restrict__ bng,
                                                   const float* __restrict__ bnb,
                                                   const float* __restrict__ bnm,
                                                   const float* __restrict__ bnv,
                                                   const __hip_bfloat16* __restrict__ hres,
                                                   __hip_bfloat16* __restrict__ hout,
                                                   int do_bn) {
    __shared__ __align__(16) __hip_bfloat16 Alds[128][136];
    __shared__ __align__(16) __hip_bfloat16 Blds[128][136];
    int t = threadIdx.x;
    int wave = t >> 6, lane = t & 63;
    int quad = lane >> 4, r16 = lane & 15;
    int m0 = blockIdx.x * 128;
    f32x4 acc[2][8];
    #pragma unroll
    for (int i = 0; i < 2; i++)
        #pragma unroll
        for (int j = 0; j < 8; j++) acc[i][j] = (f32x4){0.f, 0.f, 0.f, 0.f};

    for (int g = 0; g < 5; g++) {
        #pragma unroll
        for (int it = 0; it < 8; it++) {
            int sgi = t + it * 256;
            int row = sgi >> 4, seg = sgi & 15;
            int node = m0 + row; if (node >= NN) node = NN - 1;
            const uint4* sp = (g == 0)
                ? (const uint4*)(h_in + (size_t)node * 128)
                : (const uint4*)(xagg + (size_t)node * 512 + (size_t)(g - 1) * 128);
            uint4 val = sp[seg];
            *(uint4*)&Alds[row][seg * 8] = val;
        }
        const uint4* wp = (const uint4*)(wt + (size_t)g * 16384);
        #pragma unroll
        for (int it = 0; it < 8; it++) {
            int sgi = t + it * 256;
            int n = sgi >> 4, seg = sgi & 15;
            uint4 val = wp[n * 16 + seg];
            *(uint4*)&Blds[n][seg * 8] = val;
        }
        __syncthreads();
        #pragma unroll
        for (int kc = 0; kc < 4; kc++) {
            short8 a0 = *(const short8*)&Alds[wave * 32 + r16][kc * 32 + quad * 8];
            short8 a1 = *(const short8*)&Alds[wave * 32 + 16 + r16][kc * 32 + quad * 8];
            #pragma unroll
            for (int nt = 0; nt < 8; nt++) {
                short8 b = *(const short8*)&Blds[nt * 16 + r16][kc * 32 + quad * 8];
                acc[0][nt] = __builtin_amdgcn_mfma_f32_16x16x32_bf16(a0, b, acc[0][nt], 0, 0, 0);
                acc[1][nt] = __builtin_amdgcn_mfma_f32_16x16x32_bf16(a1, b, acc[1][nt], 0, 0, 0);
            }
        }
        __syncthreads();
    }
    // C/D layout: col = lane&15, row = quad*4 + reg
    #pragma unroll
    for (int nt = 0; nt < 8; nt++) {
        int col = nt * 16 + r16;
        float bv = bias[col];
        float gmul = 0.f, gadd = 0.f;
        if (do_bn) {
            float iva = rsqrtf(bnv[col] + 1e-5f);
            gmul = bng[col] * iva;
            gadd = bnb[col] - bnm[col] * gmul;
        }
        #pragma unroll
        for (int mt = 0; mt < 2; mt++) {
            #pragma unroll
            for (int reg = 0; reg < 4; reg++) {
                int node = m0 + wave * 32 + mt * 16 + quad * 4 + reg;
                if (node >= NN) continue;
                float v = acc[mt][nt][reg] + bv;
                if (hres) v += __bfloat162float(hres[(size_t)node * 128 + col]);
                if (do_bn) {
                    v = v * gmul + gadd;
                    v = v > 0.f ? v : expm1f(v);   // ELU alpha=1
                }
                hout[(size_t)node * 128 + col] = __float2bfloat16(v);
            }
        }
    }
}

// ---------------- global mean pool (batch sorted) ----------------
__global__ __launch_bounds__(256) void pool_kernel(const __hip_bfloat16* __restrict__ h3,
                                                   const int* __restrict__ batch,
                                                   float* __restrict__ pooled) {
    int g = blockIdx.x, t = threadIdx.x;
    int d = t & 127, half = t >> 7;
    int lo = 0, hi = NN;
    while (lo < hi) { int mid = (lo + hi) >> 1; if (batch[mid] < g) lo = mid + 1; else hi = mid; }
    int s0 = lo;
    hi = NN;
    while (lo < hi) { int mid = (lo + hi) >> 1; if (batch[mid] < g + 1) lo = mid + 1; else hi = mid; }
    int s1 = lo;
    float acc = 0.f;
    for (int n = s0 + half; n < s1; n += 2) acc += __bfloat162float(h3[(size_t)n * 128 + d]);
    __shared__ float sd[256];
    sd[t] = acc;
    __syncthreads();
    if (t < 128) {
        int c = s1 - s0;
        pooled[g * 128 + t] = (sd[t] + sd[t + 128]) / (float)(c > 0 ? c : 1);
    }
}

// ---------------- classifier + log_softmax (params from f32 block) ----------------
__global__ __launch_bounds__(64) void cls_kernel(const float* __restrict__ pooled,
                                                 const float* __restrict__ pf,
                                                 const int* __restrict__ flag,
                                                 void* __restrict__ out) {
    int g = blockIdx.x, j = threadIdx.x;   // 64 threads
    const float* w1 = pf + 1408;
    const float* b1 = pf + 9600;
    const float* w2 = pf + 9664;
    const float* b2 = pf + 10688;
    __shared__ float z[64];
    __shared__ float lg[16];
    const float* p = pooled + g * 128;
    float acc = b1[j];
    for (int d = 0; d < 128; d++) acc += p[d] * w1[d * 64 + j];
    acc = acc > 0.f ? acc : expm1f(acc);   // ELU
    z[j] = acc;
    __syncthreads();
    if (j < CCL) {
        float l = b2[j];
        for (int k = 0; k < 64; k++) l += z[k] * w2[k * 16 + j];
        lg[j] = l;
    }
    __syncthreads();
    if (j < CCL) {
        float m = lg[0];
        for (int k = 1; k < CCL; k++) m = fmaxf(m, lg[k]);
        float s = 0.f;
        for (int k = 0; k < CCL; k++) s += expf(lg[k] - m);
        float val = lg[j] - m - logf(s);
        if (flag[0]) ((__hip_bfloat16*)out)[g * CCL + j] = __float2bfloat16(val);
        else         ((float*)out)[g * CCL + j] = val;
    }
}

extern "C" void kernel_launch(void* const* d_in, const int* in_sizes, int n_in,
                              void* d_out, int out_size, void* d_ws, size_t ws_size,
                              hipStream_t stream) {
    const void* x_raw    = d_in[0];
    const int* ei        = (const int*)d_in[1];
    const int* et        = (const int*)d_in[2];
    const int* batch     = (const int*)d_in[3];
    const void* rel_raw  = d_in[4];
    const void* root_raw = d_in[5];
    const void* bias_r   = d_in[6];
    const void* bng_r    = d_in[7];
    const void* bnb_r    = d_in[8];
    const void* bnm_r    = d_in[9];
    const void* bnv_r    = d_in[10];
    const void* w1_r     = d_in[11];
    const void* b1_r     = d_in[12];
    const void* w2_r     = d_in[13];
    const void* b2_r     = d_in[14];
    const int* srcp = ei;
    const int* dstp = ei + EE;

    char* ws = (char*)d_ws;
    size_t off = 0;
    auto take = [&](size_t bytes) { size_t r = off; off += (bytes + 1023) & ~(size_t)1023; return r; };
    __hip_bfloat16* xagg = (__hip_bfloat16*)(ws + take((size_t)NN * 512 * 2));   // 102.4 MB
    __hip_bfloat16* xc   = (__hip_bfloat16*)(ws + take((size_t)NN * 128 * 2));   // 25.6 MB
    __hip_bfloat16* hA   = (__hip_bfloat16*)(ws + take((size_t)NN * 128 * 2));
    __hip_bfloat16* hB   = (__hip_bfloat16*)(ws + take((size_t)NN * 128 * 2));
    __hip_bfloat16* hC   = (__hip_bfloat16*)(ws + take((size_t)NN * 128 * 2));
    __hip_bfloat16* wt   = (__hip_bfloat16*)(ws + take((size_t)15 * 16384 * 2));
    float* pf            = (float*)(ws + take((size_t)10704 * 4));
    float* pooled        = (float*)(ws + take((size_t)GG * 128 * 4));
    int* cnt             = (int*)(ws + take((size_t)NN * 4 + 8));
    int* counter         = cnt + NN;
    int* flag            = cnt + NN + 1;
    int* startp          = (int*)(ws + take((size_t)NN * 4));
    int* wptr            = (int*)(ws + take((size_t)NN * 4));
    int* elist           = (int*)(ws + take((size_t)EE * 4));

    hipMemsetAsync(cnt, 0, (size_t)NN * 4 + 4, stream);
    sniff_kernel<<<1, 256, 0, stream>>>(x_raw, flag);
    convx_kernel<<<(NN * DD / 8 + 255) / 256, 256, 0, stream>>>(x_raw, flag, xc);
    convw_kernel<<<15, 256, 0, stream>>>(rel_raw, root_raw, flag, wt);
    convp_kernel<<<9, 256, 0, stream>>>(bias_r, bng_r, bnb_r, bnm_r, bnv_r,
                                        w1_r, b1_r, w2_r, b2_r, flag, pf);
    count_kernel<<<(EE + 255) / 256, 256, 0, stream>>>(dstp, cnt);
    alloc_kernel<<<(NN + 255) / 256, 256, 0, stream>>>(cnt, counter, startp, wptr);
    fill_kernel<<<(EE + 255) / 256, 256, 0, stream>>>(srcp, dstp, et, wptr, elist);

    const __hip_bfloat16* hin = xc;
    __hip_bfloat16* houts[3] = {hA, hB, hC};
    for (int l = 0; l < 3; l++) {
        agg_kernel<<<(NN * 64 + 255) / 256, 256, 0, stream>>>(hin, elist, startp, cnt, xagg);
        int bl = l < 2 ? l : 1;  // bn params unused for l==2
        gemm_kernel<<<(NN + 127) / 128, 256, 0, stream>>>(
            hin, xagg, wt + (size_t)l * 5 * 16384, pf + l * 128,
            pf + 384 + bl * 128, pf + 640 + bl * 128, pf + 896 + bl * 128, pf + 1152 + bl * 128,
            (l > 0) ? hin : (const __hip_bfloat16*)nullptr, houts[l], (l < 2) ? 1 : 0);
        hin = houts[l];
    }
    pool_kernel<<<GG, 256, 0, stream>>>(houts[2], batch, pooled);
    cls_kernel<<<GG, 64, 0, stream>>>(pooled, pf, flag, (void*)d_out);
}

// Round 3
// 700.599 us; speedup vs baseline: 1.0079x; 1.0079x over previous
//
#include <hip/hip_runtime.h>
#include <hip/hip_bf16.h>

// Problem constants (RelateModel_652835029255)
#define NN 100000
#define EE 600000
#define DD 128
#define GG 256
#define CCL 16

typedef __attribute__((ext_vector_type(8))) short short8;
typedef __attribute__((ext_vector_type(4))) float f32x4;
typedef const __attribute__((address_space(1))) void* gas_t;
typedef __attribute__((address_space(3))) void* las_t;

__device__ __forceinline__ void async_ld16(const void* g, void* l) {
    __builtin_amdgcn_global_load_lds((gas_t)g, (las_t)l, 16, 0, 0);
}
__device__ __forceinline__ unsigned short f2bf(float x) {
    unsigned u = __float_as_uint(x);
    unsigned r = (u + 0x7FFFu + ((u >> 16) & 1u)) >> 16;
    return (unsigned short)r;
}
__device__ __forceinline__ float bf2f(unsigned short b) {
    return __uint_as_float(((unsigned)b) << 16);
}
__device__ __forceinline__ void unpack8(uint4 v, float* f) {
    f[0] = __uint_as_float(v.x << 16); f[1] = __uint_as_float(v.x & 0xFFFF0000u);
    f[2] = __uint_as_float(v.y << 16); f[3] = __uint_as_float(v.y & 0xFFFF0000u);
    f[4] = __uint_as_float(v.z << 16); f[5] = __uint_as_float(v.z & 0xFFFF0000u);
    f[6] = __uint_as_float(v.w << 16); f[7] = __uint_as_float(v.w & 0xFFFF0000u);
}

// ---------------- dtype sniff (f32 vs bf16 tensors) ----------------
__global__ __launch_bounds__(256) void sniff_kernel(const void* __restrict__ xraw, int* __restrict__ flag) {
    int t = threadIdx.x;
    const unsigned short* u = (const unsigned short*)xraw;
    int good = 0;
    #pragma unroll
    for (int i = 0; i < 4; i++) {
        unsigned short b = u[t * 4 + i];
        int e = (b >> 7) & 0xFF;
        if (e >= 107 && e <= 130) good++;
    }
    __shared__ int sg[256];
    sg[t] = good;
    __syncthreads();
    for (int s = 128; s > 0; s >>= 1) { if (t < s) sg[t] += sg[t + s]; __syncthreads(); }
    if (t == 0) flag[0] = (sg[0] >= 900) ? 1 : 0;   // 1 = data is bf16
}

__device__ __forceinline__ float loadf(const void* p, size_t i, int isbf) {
    if (isbf) return bf2f(((const unsigned short*)p)[i]);
    return ((const float*)p)[i];
}

__global__ __launch_bounds__(256) void convx_kernel(const void* __restrict__ xraw, const int* __restrict__ flag,
                                                    __hip_bfloat16* __restrict__ xc) {
    int isbf = flag[0];
    size_t i0 = ((size_t)blockIdx.x * 256 + threadIdx.x) * 8;
    if (i0 >= (size_t)NN * DD) return;
    if (isbf) {
        *(uint4*)(xc + i0) = *(const uint4*)((const __hip_bfloat16*)xraw + i0);
    } else {
        const float* xf = (const float*)xraw;
        unsigned short o[8];
        #pragma unroll
        for (int j = 0; j < 8; j++) o[j] = f2bf(xf[i0 + j]);
        *(uint4*)(xc + i0) = *(uint4*)o;
    }
}

// weights -> wt[mat][n][k] (transposed, bf16), mat = layer*5 + g (g0=root, g1..4=rel)
__global__ __launch_bounds__(256) void convw_kernel(const void* __restrict__ rel_raw, const void* __restrict__ root_raw,
                                                    const int* __restrict__ flag, __hip_bfloat16* __restrict__ wt) {
    int isbf = flag[0];
    int mat = blockIdx.x;
    int layer = mat / 5, g = mat % 5;
    size_t srcoff = (g == 0) ? (size_t)layer * 16384 : (size_t)(layer * 4 + (g - 1)) * 16384;
    const void* sraw = (g == 0) ? root_raw : rel_raw;
    __hip_bfloat16* dstp = wt + (size_t)mat * 16384;
    for (int idx = threadIdx.x; idx < 16384; idx += 256) {
        int k = idx >> 7, n = idx & 127;
        float v = loadf(sraw, srcoff + (size_t)k * 128 + n, isbf);
        dstp[n * 128 + k] = __float2bfloat16(v);
    }
}

// small params -> one f32 block (see offsets in kernel_launch)
__global__ __launch_bounds__(256) void convp_kernel(const void* bias, const void* bng, const void* bnb,
                                                    const void* bnm, const void* bnv, const void* w1,
                                                    const void* b1, const void* w2, const void* b2,
                                                    const int* __restrict__ flag, float* __restrict__ pf) {
    int isbf = flag[0];
    const void* srcs[9] = {bias, bng, bnb, bnm, bnv, w1, b1, w2, b2};
    const int cnts[9] = {384, 256, 256, 256, 256, 8192, 64, 1024, 16};
    const int offs[9] = {0, 384, 640, 896, 1152, 1408, 9600, 9664, 10688};
    int b = blockIdx.x;
    const void* s = srcs[b];
    int c = cnts[b], o = offs[b];
    for (int i = threadIdx.x; i < c; i += 256) pf[o + i] = loadf(s, i, isbf);
}

// ---------------- CSR build ----------------
__global__ __launch_bounds__(256) void count_kernel(const int* __restrict__ dst, int* __restrict__ cnt) {
    int e = blockIdx.x * 256 + threadIdx.x;
    if (e < EE) atomicAdd(&cnt[dst[e]], 1);
}

__global__ __launch_bounds__(256) void alloc_kernel(const int* __restrict__ cnt, int* __restrict__ counter,
                                                    int* __restrict__ startp, int* __restrict__ wptr) {
    int n = blockIdx.x * 256 + threadIdx.x;
    int lane = threadIdx.x & 63;
    int c = (n < NN) ? cnt[n] : 0;
    int v = c;
    #pragma unroll
    for (int d = 1; d < 64; d <<= 1) {
        int o = __shfl_up(v, d);
        if (lane >= d) v += o;
    }
    int base = 0;
    if (lane == 63) base = atomicAdd(counter, v);
    base = __shfl(base, 63);
    if (n < NN) {
        int s = base + v - c;
        startp[n] = s;
        wptr[n]  = s;
    }
}

__global__ __launch_bounds__(256) void fill_kernel(const int* __restrict__ src, const int* __restrict__ dst,
                                                   const int* __restrict__ et, int* __restrict__ wptr,
                                                   int* __restrict__ elist) {
    int e = blockIdx.x * 256 + threadIdx.x;
    if (e < EE) {
        int d = dst[e];
        int pos = atomicAdd(&wptr[d], 1);
        elist[pos] = src[e] | (et[e] << 17);
    }
}

// ---------------- per-node mean aggregation v2 ----------------
// one wave per node; 4 lane-groups of 16 process 8 edges per iteration (2 per group in flight);
// each lane covers 8 feature cols via uint4; per-relation sums in registers; xor-shuffle combine.
__global__ __launch_bounds__(256) void agg_kernel(const __hip_bfloat16* __restrict__ h,
                                                  const int* __restrict__ elist,
                                                  const int* __restrict__ startp,
                                                  const int* __restrict__ cnt,
                                                  __hip_bfloat16* __restrict__ xagg) {
    int wid = (blockIdx.x * 256 + threadIdx.x) >> 6;
    int lane = threadIdx.x & 63;
    if (wid >= NN) return;
    int s = startp[wid], c = cnt[wid];
    int egrp = lane >> 4, col16 = lane & 15;
    int my = (lane < c) ? elist[s + lane] : 0;
    float acc[4][8];
    float cc[4] = {0.f, 0.f, 0.f, 0.f};
    #pragma unroll
    for (int rr = 0; rr < 4; rr++)
        #pragma unroll
        for (int j = 0; j < 8; j++) acc[rr][j] = 0.f;

    for (int base = 0; base < c; base += 8) {
        int eA = base + egrp, eB = base + 4 + egrp;
        bool actA = eA < c, actB = eB < c;
        int pA = __shfl(my, eA & 63);
        int pB = __shfl(my, eB & 63);
        if (actA && eA >= 64) pA = elist[s + eA];
        if (actB && eB >= 64) pB = elist[s + eB];
        int srcA = pA & 0x1FFFF, rA = (pA >> 17) & 3;
        int srcB = pB & 0x1FFFF, rB = (pB >> 17) & 3;
        uint4 vA = make_uint4(0, 0, 0, 0), vB = make_uint4(0, 0, 0, 0);
        if (actA) vA = *(const uint4*)(h + (size_t)srcA * DD + col16 * 8);
        if (actB) vB = *(const uint4*)(h + (size_t)srcB * DD + col16 * 8);
        float fA[8], fB[8];
        unpack8(vA, fA);
        unpack8(vB, fB);
        #pragma unroll
        for (int rr = 0; rr < 4; rr++) {
            float mA = (actA && rA == rr) ? 1.f : 0.f;
            float mB = (actB && rB == rr) ? 1.f : 0.f;
            cc[rr] += mA + mB;
            #pragma unroll
            for (int j = 0; j < 8; j++)
                acc[rr][j] = fmaf(mA, fA[j], fmaf(mB, fB[j], acc[rr][j]));
        }
    }
    // combine the 4 lane-groups (xor 16 then 32 sums each group exactly once)
    #pragma unroll
    for (int rr = 0; rr < 4; rr++) {
        cc[rr] += __shfl_xor(cc[rr], 16);
        cc[rr] += __shfl_xor(cc[rr], 32);
        #pragma unroll
        for (int j = 0; j < 8; j++) {
            float sv = acc[rr][j];
            sv += __shfl_xor(sv, 16);
            sv += __shfl_xor(sv, 32);
            acc[rr][j] = sv;
        }
    }
    // each lane-group writes its relation's 8 cols
    float o[8], ct;
    #pragma unroll
    for (int j = 0; j < 8; j++)
        o[j] = egrp < 2 ? (egrp == 0 ? acc[0][j] : acc[1][j])
                        : (egrp == 2 ? acc[2][j] : acc[3][j]);
    ct = egrp < 2 ? (egrp == 0 ? cc[0] : cc[1]) : (egrp == 2 ? cc[2] : cc[3]);
    float inv = 1.f / fmaxf(ct, 1.f);
    unsigned short u[8];
    #pragma unroll
    for (int j = 0; j < 8; j++) u[j] = f2bf(o[j] * inv);
    *(uint4*)(xagg + (size_t)wid * 512 + egrp * 128 + col16 * 8) = *(uint4*)u;
}

// ---------------- fused GEMM v2: out = [h | agg] @ [Wroot;W0..W3] + bias (+res,+BN,+ELU) ----
// BM=128, BN=128, BK=64, 10 K-chunks. global_load_lds (16B) staging into XOR-swizzled LDS.
// A tile 16KB + B tile 16KB (34KB total w/ params) -> 4 blocks/CU at <=128 VGPR.
__global__ __launch_bounds__(256, 4) void gemm_kernel(const __hip_bfloat16* __restrict__ h_in,
                                                      const __hip_bfloat16* __restrict__ xagg,
                                                      const __hip_bfloat16* __restrict__ wt,   // [5][128 n][128 k]
                                                      const float* __restrict__ bias,
                                                      const float* __restrict__ bng,
                                                      const float* __restrict__ bnb,
                                                      const float* __restrict__ bnm,
                                                      const float* __restrict__ bnv,
                                                      const __hip_bfloat16* __restrict__ hres,
                                                      __hip_bfloat16* __restrict__ hout,
                                                      int do_bn) {
    __shared__ __align__(16) short lds[16384];  // A:[0,8192) B:[8192,16384); reused as C[128][128] in epilogue
    __shared__ float sbias[128], sgm[128], sga[128];
    short* Ab = lds;
    short* Bb = lds + 8192;
    int t = threadIdx.x;
    int wave = t >> 6, lane = t & 63, quad = lane >> 4, r16 = lane & 15;
    int m0 = blockIdx.x * 128;

    if (t < 128) {
        sbias[t] = bias[t];
        float gm = 0.f, ga = 0.f;
        if (do_bn) {
            float iva = rsqrtf(bnv[t] + 1e-5f);
            gm = bng[t] * iva;
            ga = bnb[t] - bnm[t] * gm;
        }
        sgm[t] = gm; sga[t] = ga;
    }

    // staging geometry: slot = j*256 + t; row = slot>>3; segslot = t&7; global seg = segslot ^ (row&7)
    int rbase = t >> 3;                 // 0..31
    int gseg8 = ((t & 7) ^ (rbase & 7)) * 8;   // element offset of the 16B segment this thread fetches

    f32x4 acc[2][8];
    #pragma unroll
    for (int i = 0; i < 2; i++)
        #pragma unroll
        for (int j = 0; j < 8; j++) acc[i][j] = (f32x4){0.f, 0.f, 0.f, 0.f};

    for (int c = 0; c < 10; c++) {
        const __hip_bfloat16* asrc;
        int astride;
        if (c < 2) { asrc = h_in + c * 64; astride = 128; }
        else       { asrc = xagg + (c - 2) * 64; astride = 512; }
        const __hip_bfloat16* bsrc = wt + (size_t)(c >> 1) * 16384 + (c & 1) * 64;
        #pragma unroll
        for (int j = 0; j < 4; j++) {
            int row = j * 32 + rbase;
            int node = m0 + row; if (node > NN - 1) node = NN - 1;
            async_ld16(asrc + (size_t)node * astride + gseg8, &Ab[(j * 256 + t) * 8]);
            async_ld16(bsrc + (size_t)row * 128 + gseg8, &Bb[(j * 256 + t) * 8]);
        }
        __syncthreads();
        #pragma unroll
        for (int kc = 0; kc < 2; kc++) {
            int ra0 = wave * 32 + r16;
            int ra1 = ra0 + 16;
            short8 a0 = *(const short8*)&Ab[(ra0 * 8 + ((kc * 4 + quad) ^ (ra0 & 7))) * 8];
            short8 a1 = *(const short8*)&Ab[(ra1 * 8 + ((kc * 4 + quad) ^ (ra1 & 7))) * 8];
            #pragma unroll
            for (int nt = 0; nt < 8; nt++) {
                int rb = nt * 16 + r16;
                short8 b = *(const short8*)&Bb[(rb * 8 + ((kc * 4 + quad) ^ (rb & 7))) * 8];
                acc[0][nt] = __builtin_amdgcn_mfma_f32_16x16x32_bf16(a0, b, acc[0][nt], 0, 0, 0);
                acc[1][nt] = __builtin_amdgcn_mfma_f32_16x16x32_bf16(a1, b, acc[1][nt], 0, 0, 0);
            }
        }
        __syncthreads();
    }

    // ---- epilogue: repack C through LDS (swizzled [128][16 segs], seg' = seg ^ (row&15)) ----
    #pragma unroll
    for (int nt = 0; nt < 8; nt++) {
        int col = nt * 16 + r16;
        float bv = sbias[col];
        #pragma unroll
        for (int mt = 0; mt < 2; mt++) {
            #pragma unroll
            for (int reg = 0; reg < 4; reg++) {
                int row = wave * 32 + mt * 16 + quad * 4 + reg;
                int sslot = (col >> 3) ^ (row & 15);
                lds[row * 128 + sslot * 8 + (col & 7)] = (short)f2bf(acc[mt][nt][reg] + bv);
            }
        }
    }
    __syncthreads();
    int row = t >> 1, half = t & 1;
    int node = m0 + row;
    if (node < NN) {
        #pragma unroll
        for (int q = 0; q < 8; q++) {
            int seg = half * 8 + q;
            int sslot = seg ^ (row & 15);
            short8 cv = *(const short8*)&lds[row * 128 + sslot * 8];
            int col0 = seg * 8;
            float v[8];
            #pragma unroll
            for (int j = 0; j < 8; j++) v[j] = bf2f((unsigned short)cv[j]);
            if (hres) {
                float rf[8];
                unpack8(*(const uint4*)(hres + (size_t)node * 128 + col0), rf);
                #pragma unroll
                for (int j = 0; j < 8; j++) v[j] += rf[j];
            }
            if (do_bn) {
                #pragma unroll
                for (int j = 0; j < 8; j++) {
                    float z = v[j] * sgm[col0 + j] + sga[col0 + j];
                    v[j] = z > 0.f ? z : expm1f(z);
                }
            }
            unsigned short u[8];
            #pragma unroll
            for (int j = 0; j < 8; j++) u[j] = f2bf(v[j]);
            *(uint4*)(hout + (size_t)node * 128 + col0) = *(uint4*)u;
        }
    }
}

// ---------------- global mean pool v2 (batch sorted) ----------------
__global__ __launch_bounds__(256) void pool_kernel(const __hip_bfloat16* __restrict__ h3,
                                                   const int* __restrict__ batch,
                                                   float* __restrict__ pooled) {
    int g = blockIdx.x, t = threadIdx.x;
    int rowpar = t >> 4, colg = t & 15;
    int lo = 0, hi = NN;
    while (lo < hi) { int mid = (lo + hi) >> 1; if (batch[mid] < g) lo = mid + 1; else hi = mid; }
    int s0 = lo;
    hi = NN;
    while (lo < hi) { int mid = (lo + hi) >> 1; if (batch[mid] < g + 1) lo = mid + 1; else hi = mid; }
    int s1 = lo;
    float a[8];
    #pragma unroll
    for (int j = 0; j < 8; j++) a[j] = 0.f;
    for (int n = s0 + rowpar; n < s1; n += 16) {
        float f[8];
        unpack8(*(const uint4*)(h3 + (size_t)n * 128 + colg * 8), f);
        #pragma unroll
        for (int j = 0; j < 8; j++) a[j] += f[j];
    }
    __shared__ float sd[16][128];
    #pragma unroll
    for (int j = 0; j < 8; j++) sd[rowpar][colg * 8 + j] = a[j];
    __syncthreads();
    if (t < 128) {
        float sum = 0.f;
        #pragma unroll
        for (int i = 0; i < 16; i++) sum += sd[i][t];
        int cgn = s1 - s0;
        pooled[g * 128 + t] = sum / (float)(cgn > 0 ? cgn : 1);
    }
}

// ---------------- classifier + log_softmax ----------------
__global__ __launch_bounds__(64) void cls_kernel(const float* __restrict__ pooled,
                                                 const float* __restrict__ pf,
                                                 const int* __restrict__ flag,
                                                 void* __restrict__ out) {
    int g = blockIdx.x, j = threadIdx.x;
    const float* w1 = pf + 1408;
    const float* b1 = pf + 9600;
    const float* w2 = pf + 9664;
    const float* b2 = pf + 10688;
    __shared__ float z[64];
    __shared__ float lg[16];
    const float* p = pooled + g * 128;
    float acc = b1[j];
    for (int d = 0; d < 128; d++) acc += p[d] * w1[d * 64 + j];
    acc = acc > 0.f ? acc : expm1f(acc);
    z[j] = acc;
    __syncthreads();
    if (j < CCL) {
        float l = b2[j];
        for (int k = 0; k < 64; k++) l += z[k] * w2[k * 16 + j];
        lg[j] = l;
    }
    __syncthreads();
    if (j < CCL) {
        float m = lg[0];
        for (int k = 1; k < CCL; k++) m = fmaxf(m, lg[k]);
        float s = 0.f;
        for (int k = 0; k < CCL; k++) s += expf(lg[k] - m);
        float val = lg[j] - m - logf(s);
        if (flag[0]) ((__hip_bfloat16*)out)[g * CCL + j] = __float2bfloat16(val);
        else         ((float*)out)[g * CCL + j] = val;
    }
}

extern "C" void kernel_launch(void* const* d_in, const int* in_sizes, int n_in,
                              void* d_out, int out_size, void* d_ws, size_t ws_size,
                              hipStream_t stream) {
    const void* x_raw    = d_in[0];
    const int* ei        = (const int*)d_in[1];
    const int* et        = (const int*)d_in[2];
    const int* batch     = (const int*)d_in[3];
    const void* rel_raw  = d_in[4];
    const void* root_raw = d_in[5];
    const int* srcp = ei;
    const int* dstp = ei + EE;

    char* ws = (char*)d_ws;
    size_t off = 0;
    auto take = [&](size_t bytes) { size_t r = off; off += (bytes + 1023) & ~(size_t)1023; return r; };
    __hip_bfloat16* xagg = (__hip_bfloat16*)(ws + take((size_t)NN * 512 * 2));
    __hip_bfloat16* xc   = (__hip_bfloat16*)(ws + take((size_t)NN * 128 * 2));
    __hip_bfloat16* hA   = (__hip_bfloat16*)(ws + take((size_t)NN * 128 * 2));
    __hip_bfloat16* hB   = (__hip_bfloat16*)(ws + take((size_t)NN * 128 * 2));
    __hip_bfloat16* hC   = (__hip_bfloat16*)(ws + take((size_t)NN * 128 * 2));
    __hip_bfloat16* wt   = (__hip_bfloat16*)(ws + take((size_t)15 * 16384 * 2));
    float* pf            = (float*)(ws + take((size_t)10704 * 4));
    float* pooled        = (float*)(ws + take((size_t)GG * 128 * 4));
    int* cnt             = (int*)(ws + take((size_t)NN * 4 + 8));
    int* counter         = cnt + NN;
    int* flag            = cnt + NN + 1;
    int* startp          = (int*)(ws + take((size_t)NN * 4));
    int* wptr            = (int*)(ws + take((size_t)NN * 4));
    int* elist           = (int*)(ws + take((size_t)EE * 4));

    hipMemsetAsync(cnt, 0, (size_t)NN * 4 + 4, stream);
    sniff_kernel<<<1, 256, 0, stream>>>(x_raw, flag);
    convx_kernel<<<(NN * DD / 8 + 255) / 256, 256, 0, stream>>>(x_raw, flag, xc);
    convw_kernel<<<15, 256, 0, stream>>>(rel_raw, root_raw, flag, wt);
    convp_kernel<<<9, 256, 0, stream>>>(d_in[6], d_in[7], d_in[8], d_in[9], d_in[10],
                                        d_in[11], d_in[12], d_in[13], d_in[14], flag, pf);
    count_kernel<<<(EE + 255) / 256, 256, 0, stream>>>(dstp, cnt);
    alloc_kernel<<<(NN + 255) / 256, 256, 0, stream>>>(cnt, counter, startp, wptr);
    fill_kernel<<<(EE + 255) / 256, 256, 0, stream>>>(srcp, dstp, et, wptr, elist);

    const __hip_bfloat16* hin = xc;
    __hip_bfloat16* houts[3] = {hA, hB, hC};
    for (int l = 0; l < 3; l++) {
        agg_kernel<<<(NN * 64 + 255) / 256, 256, 0, stream>>>(hin, elist, startp, cnt, xagg);
        int bl = l < 2 ? l : 1;
        gemm_kernel<<<(NN + 127) / 128, 256, 0, stream>>>(
            hin, xagg, wt + (size_t)l * 5 * 16384, pf + l * 128,
            pf + 384 + bl * 128, pf + 640 + bl * 128, pf + 896 + bl * 128, pf + 1152 + bl * 128,
            (l > 0) ? hin : (const __hip_bfloat16*)nullptr, houts[l], (l < 2) ? 1 : 0);
        hin = houts[l];
    }
    pool_kernel<<<GG, 256, 0, stream>>>(houts[2], batch, pooled);
    cls_kernel<<<GG, 64, 0, stream>>>(pooled, pf, flag, (void*)d_out);
}

// Round 4
// 635.997 us; speedup vs baseline: 1.1103x; 1.1016x over previous
//
#include <hip/hip_runtime.h>
#include <hip/hip_bf16.h>

// Problem constants (RelateModel_652835029255)
#define NN 100000
#define EE 600000
#define DD 128
#define GG 256
#define CCL 16

typedef __attribute__((ext_vector_type(8))) short short8;
typedef __attribute__((ext_vector_type(4))) float f32x4;
typedef const __attribute__((address_space(1))) void* gas_t;
typedef __attribute__((address_space(3))) void* las_t;

__device__ __forceinline__ void async_ld16(const void* g, void* l) {
    __builtin_amdgcn_global_load_lds((gas_t)g, (las_t)l, 16, 0, 0);
}
__device__ __forceinline__ unsigned short f2bf(float x) {
    unsigned u = __float_as_uint(x);
    unsigned r = (u + 0x7FFFu + ((u >> 16) & 1u)) >> 16;
    return (unsigned short)r;
}
__device__ __forceinline__ float bf2f(unsigned short b) {
    return __uint_as_float(((unsigned)b) << 16);
}
__device__ __forceinline__ void unpack8(uint4 v, float* f) {
    f[0] = __uint_as_float(v.x << 16); f[1] = __uint_as_float(v.x & 0xFFFF0000u);
    f[2] = __uint_as_float(v.y << 16); f[3] = __uint_as_float(v.y & 0xFFFF0000u);
    f[4] = __uint_as_float(v.z << 16); f[5] = __uint_as_float(v.z & 0xFFFF0000u);
    f[6] = __uint_as_float(v.w << 16); f[7] = __uint_as_float(v.w & 0xFFFF0000u);
}

// ---------------- dtype sniff (f32 vs bf16 tensors) ----------------
__global__ __launch_bounds__(256) void sniff_kernel(const void* __restrict__ xraw, int* __restrict__ flag) {
    int t = threadIdx.x;
    const unsigned short* u = (const unsigned short*)xraw;
    int good = 0;
    #pragma unroll
    for (int i = 0; i < 4; i++) {
        unsigned short b = u[t * 4 + i];
        int e = (b >> 7) & 0xFF;
        if (e >= 107 && e <= 130) good++;
    }
    __shared__ int sg[256];
    sg[t] = good;
    __syncthreads();
    for (int s = 128; s > 0; s >>= 1) { if (t < s) sg[t] += sg[t + s]; __syncthreads(); }
    if (t == 0) flag[0] = (sg[0] >= 900) ? 1 : 0;   // 1 = data is bf16
}

__device__ __forceinline__ float loadf(const void* p, size_t i, int isbf) {
    if (isbf) return bf2f(((const unsigned short*)p)[i]);
    return ((const float*)p)[i];
}

__global__ __launch_bounds__(256) void convx_kernel(const void* __restrict__ xraw, const int* __restrict__ flag,
                                                    __hip_bfloat16* __restrict__ xc) {
    int isbf = flag[0];
    size_t i0 = ((size_t)blockIdx.x * 256 + threadIdx.x) * 8;
    if (i0 >= (size_t)NN * DD) return;
    if (isbf) {
        *(uint4*)(xc + i0) = *(const uint4*)((const __hip_bfloat16*)xraw + i0);
    } else {
        const float* xf = (const float*)xraw;
        unsigned short o[8];
        #pragma unroll
        for (int j = 0; j < 8; j++) o[j] = f2bf(xf[i0 + j]);
        *(uint4*)(xc + i0) = *(uint4*)o;
    }
}

// weights -> wt[mat][n][k] (transposed, bf16), mat = layer*5 + g (g0=root, g1..4=rel)
__global__ __launch_bounds__(256) void convw_kernel(const void* __restrict__ rel_raw, const void* __restrict__ root_raw,
                                                    const int* __restrict__ flag, __hip_bfloat16* __restrict__ wt) {
    int isbf = flag[0];
    int mat = blockIdx.x;
    int layer = mat / 5, g = mat % 5;
    size_t srcoff = (g == 0) ? (size_t)layer * 16384 : (size_t)(layer * 4 + (g - 1)) * 16384;
    const void* sraw = (g == 0) ? root_raw : rel_raw;
    __hip_bfloat16* dstp = wt + (size_t)mat * 16384;
    for (int idx = threadIdx.x; idx < 16384; idx += 256) {
        int k = idx >> 7, n = idx & 127;
        float v = loadf(sraw, srcoff + (size_t)k * 128 + n, isbf);
        dstp[n * 128 + k] = __float2bfloat16(v);
    }
}

// small params -> one f32 block
__global__ __launch_bounds__(256) void convp_kernel(const void* bias, const void* bng, const void* bnb,
                                                    const void* bnm, const void* bnv, const void* w1,
                                                    const void* b1, const void* w2, const void* b2,
                                                    const int* __restrict__ flag, float* __restrict__ pf) {
    int isbf = flag[0];
    const void* srcs[9] = {bias, bng, bnb, bnm, bnv, w1, b1, w2, b2};
    const int cnts[9] = {384, 256, 256, 256, 256, 8192, 64, 1024, 16};
    const int offs[9] = {0, 384, 640, 896, 1152, 1408, 9600, 9664, 10688};
    int b = blockIdx.x;
    const void* s = srcs[b];
    int c = cnts[b], o = offs[b];
    for (int i = threadIdx.x; i < c; i += 256) pf[o + i] = loadf(s, i, isbf);
}

// ---------------- CSR build, relation-sorted: segments keyed by (dst, rel) ----------------
__global__ __launch_bounds__(256) void count4_kernel(const int* __restrict__ dst, const int* __restrict__ et,
                                                     int* __restrict__ cnt4) {
    int e = blockIdx.x * 256 + threadIdx.x;
    if (e < EE) atomicAdd(&cnt4[dst[e] * 4 + et[e]], 1);
}

// scan over 400000 (dst,rel) counters; each wave handles 256 entries (4/lane), 1 atomic/wave.
__global__ __launch_bounds__(256) void alloc4_kernel(const int* __restrict__ cnt4, int* __restrict__ counter,
                                                     int* __restrict__ startp4, int* __restrict__ wptr4) {
    int wgid = blockIdx.x * 4 + (threadIdx.x >> 6);
    int lane = threadIdx.x & 63;
    int e0 = wgid * 256 + lane * 4;
    int4 cv = make_int4(0, 0, 0, 0);
    if (e0 < NN * 4) cv = *(const int4*)(cnt4 + e0);
    int c = cv.x + cv.y + cv.z + cv.w;
    int v = c;
    #pragma unroll
    for (int d = 1; d < 64; d <<= 1) {
        int o = __shfl_up(v, d);
        if (lane >= d) v += o;
    }
    int base = 0;
    if (lane == 63) base = atomicAdd(counter, v);
    base = __shfl(base, 63);
    if (e0 < NN * 4) {
        int s0 = base + v - c;
        int4 st;
        st.x = s0; st.y = s0 + cv.x; st.z = st.y + cv.y; st.w = st.z + cv.z;
        *(int4*)(startp4 + e0) = st;
        *(int4*)(wptr4 + e0) = st;
    }
}

__global__ __launch_bounds__(256) void fill4_kernel(const int* __restrict__ src, const int* __restrict__ dst,
                                                    const int* __restrict__ et, int* __restrict__ wptr4,
                                                    int* __restrict__ elist) {
    int e = blockIdx.x * 256 + threadIdx.x;
    if (e < EE) {
        int pos = atomicAdd(&wptr4[dst[e] * 4 + et[e]], 1);
        elist[pos] = src[e];
    }
}

// ---------------- per-node mean aggregation v3 ----------------
// 16-lane group per node (16 groups/block). Rel-sorted segments: pure sums, no masks/shuffles.
__global__ __launch_bounds__(256) void agg_kernel(const __hip_bfloat16* __restrict__ h,
                                                  const int* __restrict__ elist,
                                                  const int* __restrict__ startp4,
                                                  const int* __restrict__ cnt4,
                                                  __hip_bfloat16* __restrict__ xagg) {
    int node = blockIdx.x * 16 + (threadIdx.x >> 4);   // grid = 6250 -> exact
    int c16 = threadIdx.x & 15;
    const int* st = startp4 + node * 4;
    const int* cn = cnt4 + node * 4;
    __hip_bfloat16* outp = xagg + (size_t)node * 512;
    #pragma unroll
    for (int r = 0; r < 4; r++) {
        int s = st[r], c = cn[r];
        float a[8];
        #pragma unroll
        for (int j = 0; j < 8; j++) a[j] = 0.f;
        for (int i = 0; i < c; i++) {
            int srcn = elist[s + i];                   // same addr across group: HW broadcast
            uint4 v = *(const uint4*)(h + (size_t)srcn * DD + c16 * 8);
            float f[8];
            unpack8(v, f);
            #pragma unroll
            for (int j = 0; j < 8; j++) a[j] += f[j];
        }
        float inv = 1.f / (float)(c > 0 ? c : 1);
        unsigned short u[8];
        #pragma unroll
        for (int j = 0; j < 8; j++) u[j] = f2bf(a[j] * inv);
        *(uint4*)(outp + r * 128 + c16 * 8) = *(uint4*)u;
    }
}

// ---------------- fused GEMM v3: out = [h | agg] @ [Wroot;W0..W3] + bias (+res,+BN,+ELU) ----
// Per weight-mat g (5): stage B(128x128) via global_load_lds into XOR-swizzled LDS (1 barrier),
// A fragments direct global->VGPR (no LDS), 64 MFMA per window, barrier before restage.
__global__ __launch_bounds__(256) void gemm_kernel(const __hip_bfloat16* __restrict__ h_in,
                                                   const __hip_bfloat16* __restrict__ xagg,
                                                   const __hip_bfloat16* __restrict__ wt,   // [5][128 n][128 k]
                                                   const float* __restrict__ bias,
                                                   const float* __restrict__ bng,
                                                   const float* __restrict__ bnb,
                                                   const float* __restrict__ bnm,
                                                   const float* __restrict__ bnv,
                                                   const __hip_bfloat16* __restrict__ hres,
                                                   __hip_bfloat16* __restrict__ hout,
                                                   int do_bn) {
    __shared__ __align__(16) short lds[16384];  // B stage (32KB); reused as C repack in epilogue
    __shared__ float sbias[128], sgm[128], sga[128];
    int t = threadIdx.x;
    int wave = t >> 6, lane = t & 63, quad = lane >> 4, r16 = lane & 15;
    int m0 = blockIdx.x * 128;

    if (t < 128) {
        sbias[t] = bias[t];
        float gm = 0.f, ga = 0.f;
        if (do_bn) {
            float iva = rsqrtf(bnv[t] + 1e-5f);
            gm = bng[t] * iva;
            ga = bnb[t] - bnm[t] * gm;
        }
        sgm[t] = gm; sga[t] = ga;
    }

    int r0 = m0 + wave * 32 + r16;      if (r0 > NN - 1) r0 = NN - 1;
    int r1 = m0 + wave * 32 + 16 + r16; if (r1 > NN - 1) r1 = NN - 1;

    f32x4 acc[2][8];
    #pragma unroll
    for (int i = 0; i < 2; i++)
        #pragma unroll
        for (int j = 0; j < 8; j++) acc[i][j] = (f32x4){0.f, 0.f, 0.f, 0.f};

    #pragma unroll
    for (int g = 0; g < 5; g++) {
        // stage B: slot -> (row=slot>>4, s'=slot&15), fetch global seg s'^(row&15)
        const __hip_bfloat16* wg = wt + (size_t)g * 16384;
        #pragma unroll
        for (int j = 0; j < 8; j++) {
            int slot = j * 256 + t;
            int row = slot >> 4, sp = slot & 15;
            int sg = sp ^ (row & 15);
            async_ld16(wg + row * 128 + sg * 8, &lds[slot * 8]);
        }
        __syncthreads();   // vmcnt drain -> B visible

        const __hip_bfloat16* a0p = (g == 0) ? (h_in + (size_t)r0 * 128)
                                             : (xagg + (size_t)r0 * 512 + (g - 1) * 128);
        const __hip_bfloat16* a1p = (g == 0) ? (h_in + (size_t)r1 * 128)
                                             : (xagg + (size_t)r1 * 512 + (g - 1) * 128);
        #pragma unroll
        for (int kc = 0; kc < 4; kc++) {
            short8 a0 = *(const short8*)(a0p + kc * 32 + quad * 8);
            short8 a1 = *(const short8*)(a1p + kc * 32 + quad * 8);
            int s = kc * 4 + quad;
            #pragma unroll
            for (int nt = 0; nt < 8; nt++) {
                int rb = nt * 16 + r16;
                short8 b = *(const short8*)&lds[(rb * 16 + (s ^ (rb & 15))) * 8];
                acc[0][nt] = __builtin_amdgcn_mfma_f32_16x16x32_bf16(a0, b, acc[0][nt], 0, 0, 0);
                acc[1][nt] = __builtin_amdgcn_mfma_f32_16x16x32_bf16(a1, b, acc[1][nt], 0, 0, 0);
            }
        }
        __syncthreads();   // before restage / epilogue reuse
    }

    // ---- epilogue: repack C through LDS (swizzled), coalesced dwordx4 stores ----
    #pragma unroll
    for (int nt = 0; nt < 8; nt++) {
        int col = nt * 16 + r16;
        float bv = sbias[col];
        #pragma unroll
        for (int mt = 0; mt < 2; mt++) {
            #pragma unroll
            for (int reg = 0; reg < 4; reg++) {
                int row = wave * 32 + mt * 16 + quad * 4 + reg;
                int sslot = (col >> 3) ^ (row & 15);
                lds[row * 128 + sslot * 8 + (col & 7)] = (short)f2bf(acc[mt][nt][reg] + bv);
            }
        }
    }
    __syncthreads();
    int row = t >> 1, half = t & 1;
    int node = m0 + row;
    if (node < NN) {
        #pragma unroll
        for (int q = 0; q < 8; q++) {
            int seg = half * 8 + q;
            int sslot = seg ^ (row & 15);
            short8 cv = *(const short8*)&lds[row * 128 + sslot * 8];
            int col0 = seg * 8;
            float v[8];
            #pragma unroll
            for (int j = 0; j < 8; j++) v[j] = bf2f((unsigned short)cv[j]);
            if (hres) {
                float rf[8];
                unpack8(*(const uint4*)(hres + (size_t)node * 128 + col0), rf);
                #pragma unroll
                for (int j = 0; j < 8; j++) v[j] += rf[j];
            }
            if (do_bn) {
                #pragma unroll
                for (int j = 0; j < 8; j++) {
                    float z = v[j] * sgm[col0 + j] + sga[col0 + j];
                    v[j] = z > 0.f ? z : expm1f(z);
                }
            }
            unsigned short u[8];
            #pragma unroll
            for (int j = 0; j < 8; j++) u[j] = f2bf(v[j]);
            *(uint4*)(hout + (size_t)node * 128 + col0) = *(uint4*)u;
        }
    }
}

// ---------------- global mean pool (batch sorted) ----------------
__global__ __launch_bounds__(256) void pool_kernel(const __hip_bfloat16* __restrict__ h3,
                                                   const int* __restrict__ batch,
                                                   float* __restrict__ pooled) {
    int g = blockIdx.x, t = threadIdx.x;
    int rowpar = t >> 4, colg = t & 15;
    int lo = 0, hi = NN;
    while (lo < hi) { int mid = (lo + hi) >> 1; if (batch[mid] < g) lo = mid + 1; else hi = mid; }
    int s0 = lo;
    hi = NN;
    while (lo < hi) { int mid = (lo + hi) >> 1; if (batch[mid] < g + 1) lo = mid + 1; else hi = mid; }
    int s1 = lo;
    float a[8];
    #pragma unroll
    for (int j = 0; j < 8; j++) a[j] = 0.f;
    for (int n = s0 + rowpar; n < s1; n += 16) {
        float f[8];
        unpack8(*(const uint4*)(h3 + (size_t)n * 128 + colg * 8), f);
        #pragma unroll
        for (int j = 0; j < 8; j++) a[j] += f[j];
    }
    __shared__ float sd[16][128];
    #pragma unroll
    for (int j = 0; j < 8; j++) sd[rowpar][colg * 8 + j] = a[j];
    __syncthreads();
    if (t < 128) {
        float sum = 0.f;
        #pragma unroll
        for (int i = 0; i < 16; i++) sum += sd[i][t];
        int cgn = s1 - s0;
        pooled[g * 128 + t] = sum / (float)(cgn > 0 ? cgn : 1);
    }
}

// ---------------- classifier + log_softmax ----------------
__global__ __launch_bounds__(64) void cls_kernel(const float* __restrict__ pooled,
                                                 const float* __restrict__ pf,
                                                 const int* __restrict__ flag,
                                                 void* __restrict__ out) {
    int g = blockIdx.x, j = threadIdx.x;
    const float* w1 = pf + 1408;
    const float* b1 = pf + 9600;
    const float* w2 = pf + 9664;
    const float* b2 = pf + 10688;
    __shared__ float z[64];
    __shared__ float lg[16];
    const float* p = pooled + g * 128;
    float acc = b1[j];
    for (int d = 0; d < 128; d++) acc += p[d] * w1[d * 64 + j];
    acc = acc > 0.f ? acc : expm1f(acc);
    z[j] = acc;
    __syncthreads();
    if (j < CCL) {
        float l = b2[j];
        for (int k = 0; k < 64; k++) l += z[k] * w2[k * 16 + j];
        lg[j] = l;
    }
    __syncthreads();
    if (j < CCL) {
        float m = lg[0];
        for (int k = 1; k < CCL; k++) m = fmaxf(m, lg[k]);
        float s = 0.f;
        for (int k = 0; k < CCL; k++) s += expf(lg[k] - m);
        float val = lg[j] - m - logf(s);
        if (flag[0]) ((__hip_bfloat16*)out)[g * CCL + j] = __float2bfloat16(val);
        else         ((float*)out)[g * CCL + j] = val;
    }
}

extern "C" void kernel_launch(void* const* d_in, const int* in_sizes, int n_in,
                              void* d_out, int out_size, void* d_ws, size_t ws_size,
                              hipStream_t stream) {
    const void* x_raw    = d_in[0];
    const int* ei        = (const int*)d_in[1];
    const int* et        = (const int*)d_in[2];
    const int* batch     = (const int*)d_in[3];
    const void* rel_raw  = d_in[4];
    const void* root_raw = d_in[5];
    const int* srcp = ei;
    const int* dstp = ei + EE;

    char* ws = (char*)d_ws;
    size_t off = 0;
    auto take = [&](size_t bytes) { size_t r = off; off += (bytes + 1023) & ~(size_t)1023; return r; };
    __hip_bfloat16* xagg = (__hip_bfloat16*)(ws + take((size_t)NN * 512 * 2));
    __hip_bfloat16* xc   = (__hip_bfloat16*)(ws + take((size_t)NN * 128 * 2));
    __hip_bfloat16* hA   = (__hip_bfloat16*)(ws + take((size_t)NN * 128 * 2));
    __hip_bfloat16* hB   = (__hip_bfloat16*)(ws + take((size_t)NN * 128 * 2));
    __hip_bfloat16* hC   = (__hip_bfloat16*)(ws + take((size_t)NN * 128 * 2));
    __hip_bfloat16* wt   = (__hip_bfloat16*)(ws + take((size_t)15 * 16384 * 2));
    float* pf            = (float*)(ws + take((size_t)10704 * 4));
    float* pooled        = (float*)(ws + take((size_t)GG * 128 * 4));
    int* cnt4            = (int*)(ws + take((size_t)NN * 16 + 8));
    int* counter         = cnt4 + NN * 4;
    int* flag            = cnt4 + NN * 4 + 1;
    int* startp4         = (int*)(ws + take((size_t)NN * 16));
    int* wptr4           = (int*)(ws + take((size_t)NN * 16));
    int* elist           = (int*)(ws + take((size_t)EE * 4));

    hipMemsetAsync(cnt4, 0, (size_t)NN * 16 + 4, stream);
    sniff_kernel<<<1, 256, 0, stream>>>(x_raw, flag);
    convx_kernel<<<(NN * DD / 8 + 255) / 256, 256, 0, stream>>>(x_raw, flag, xc);
    convw_kernel<<<15, 256, 0, stream>>>(rel_raw, root_raw, flag, wt);
    convp_kernel<<<9, 256, 0, stream>>>(d_in[6], d_in[7], d_in[8], d_in[9], d_in[10],
                                        d_in[11], d_in[12], d_in[13], d_in[14], flag, pf);
    count4_kernel<<<(EE + 255) / 256, 256, 0, stream>>>(dstp, et, cnt4);
    alloc4_kernel<<<(NN * 4 + 1023) / 1024, 256, 0, stream>>>(cnt4, counter, startp4, wptr4);
    fill4_kernel<<<(EE + 255) / 256, 256, 0, stream>>>(srcp, dstp, et, wptr4, elist);

    const __hip_bfloat16* hin = xc;
    __hip_bfloat16* houts[3] = {hA, hB, hC};
    for (int l = 0; l < 3; l++) {
        agg_kernel<<<NN / 16, 256, 0, stream>>>(hin, elist, startp4, cnt4, xagg);
        int bl = l < 2 ? l : 1;
        gemm_kernel<<<(NN + 127) / 128, 256, 0, stream>>>(
            hin, xagg, wt + (size_t)l * 5 * 16384, pf + l * 128,
            pf + 384 + bl * 128, pf + 640 + bl * 128, pf + 896 + bl * 128, pf + 1152 + bl * 128,
            (l > 0) ? hin : (const __hip_bfloat16*)nullptr, houts[l], (l < 2) ? 1 : 0);
        hin = houts[l];
    }
    pool_kernel<<<GG, 256, 0, stream>>>(houts[2], batch, pooled);
    cls_kernel<<<GG, 64, 0, stream>>>(pooled, pf, flag, (void*)d_out);
}